// Round 2
// baseline (2846.021 us; speedup 1.0000x reference)
//
#include <hip/hip_runtime.h>

#define BATCH 512
#define TLEN 128
#define DIN 512
#define HID 256
#define NCLS 96
#define STEPS 26
#define GRUIN 608
#define G3 768

#define BM 64
#define BN 64
#define BK 16
#define LDS_STRIDE 68  // 68*4 = 272 bytes, multiple of 16 -> aligned float4 rows

__device__ __forceinline__ float fast_tanh(float x) {
    return 1.f - 2.f / (__expf(2.f * x) + 1.f);
}
__device__ __forceinline__ float fast_sigmoid(float x) {
    return 1.f / (1.f + __expf(-x));
}
__device__ __forceinline__ unsigned short f2bf_rne(float f) {
    unsigned int u = __float_as_uint(f);
    unsigned int r = (u + 0x7FFFu + ((u >> 16) & 1u)) >> 16;
    return (unsigned short)r;
}
__device__ __forceinline__ float bf2f(unsigned short h) {
    return __uint_as_float(((unsigned int)h) << 16);
}

template <typename OutT>
__device__ __forceinline__ void store_c(OutT* p, float v);
template <> __device__ __forceinline__ void store_c<float>(float* p, float v) { *p = v; }
template <> __device__ __forceinline__ void store_c<unsigned short>(unsigned short* p, float v) { *p = f2bf_rne(v); }

// C[M,N] = A[M,K] @ B[N,K]^T (+ bias[n]); torch weight layout for B.
template <typename OutT>
__global__ __launch_bounds__(256)
void gemm_nt(const float* __restrict__ A, int lda,
             const float* __restrict__ Bw, int ldb,
             OutT* __restrict__ Cc, int ldc,
             const float* __restrict__ bias,
             int M, int N, int K) {
    __shared__ float As[BK][LDS_STRIDE];
    __shared__ float Bs[BK][LDS_STRIDE];
    const int tid = threadIdx.x;
    const int bm = blockIdx.x * BM;
    const int bn = blockIdx.y * BN;
    const int tx = tid & 15, ty = tid >> 4;
    const int lr = tid >> 2;
    const int lc = (tid & 3) << 2;
    float acc[4][4] = {};
    const int gr = bm + lr;
    const int gn = bn + lr;
    const float* Arow = A + (size_t)gr * lda;
    const float* Brow = Bw + (size_t)gn * ldb;
    for (int k0 = 0; k0 < K; k0 += BK) {
        float4 va = make_float4(0.f, 0.f, 0.f, 0.f);
        float4 vb = make_float4(0.f, 0.f, 0.f, 0.f);
        if (gr < M) va = *(const float4*)(Arow + k0 + lc);
        if (gn < N) vb = *(const float4*)(Brow + k0 + lc);
        As[lc + 0][lr] = va.x; As[lc + 1][lr] = va.y;
        As[lc + 2][lr] = va.z; As[lc + 3][lr] = va.w;
        Bs[lc + 0][lr] = vb.x; Bs[lc + 1][lr] = vb.y;
        Bs[lc + 2][lr] = vb.z; Bs[lc + 3][lr] = vb.w;
        __syncthreads();
#pragma unroll
        for (int k = 0; k < BK; ++k) {
            float4 a4 = *(const float4*)(&As[k][ty << 2]);
            float4 b4 = *(const float4*)(&Bs[k][tx << 2]);
            float a[4] = {a4.x, a4.y, a4.z, a4.w};
            float b[4] = {b4.x, b4.y, b4.z, b4.w};
#pragma unroll
            for (int i = 0; i < 4; ++i)
#pragma unroll
                for (int j = 0; j < 4; ++j)
                    acc[i][j] = fmaf(a[i], b[j], acc[i][j]);
        }
        __syncthreads();
    }
#pragma unroll
    for (int i = 0; i < 4; ++i) {
        int m = bm + (ty << 2) + i;
        if (m >= M) continue;
#pragma unroll
        for (int j = 0; j < 4; ++j) {
            int n = bn + (tx << 2) + j;
            if (n < N) store_c(&Cc[(size_t)m * ldc + n], acc[i][j] + (bias ? bias[n] : 0.f));
        }
    }
}

// Build Wcat = [W_h2h; W_hh], bcat = [b_h2h; b_hh]; also zero `hidden`.
__global__ __launch_bounds__(256)
void prep_wcat(const float* __restrict__ W_h2h, const float* __restrict__ W_hh,
               const float* __restrict__ b_h2h, const float* __restrict__ b_hh,
               float* __restrict__ Wcat, float* __restrict__ bcat,
               float* __restrict__ hidden) {
    int idx = blockIdx.x * 256 + threadIdx.x;   // 1024*256 total
    int r = idx >> 8, c = idx & 255;
    Wcat[idx] = (r < 256) ? W_h2h[r * 256 + c] : W_hh[(r - 256) * 256 + c];
    if (idx < 1024) bcat[idx] = (idx < 256) ? b_h2h[idx] : b_hh[idx - 256];
    if (idx < BATCH * HID) hidden[idx] = 0.f;
}

// One block per batch row b; HT = float or ushort(bf16) Hproj storage.
template <typename HT>
__global__ __launch_bounds__(256)
void attn_step(const HT* __restrict__ Hproj,     // [B,T,HID]
               const float* __restrict__ batchH, // [B,T,DIN]
               const float* __restrict__ hg,     // [B,1024]; cols 0..255 = h_proj
               const float* __restrict__ Wscore, // [HID]
               float* __restrict__ context) {    // [B,DIN]
    const int b = blockIdx.x;
    const int tid = threadIdx.x;   // 256
    __shared__ float hp[HID];
    __shared__ float wsc[HID];
    __shared__ float es[TLEN];
    __shared__ float red[16];
    hp[tid] = hg[b * 1024 + tid];
    wsc[tid] = Wscore[tid];
    __syncthreads();
    const int wave = tid >> 6;
    const int lane = tid & 63;
    const HT* Hp = Hproj + (size_t)b * TLEN * HID;
    for (int t = wave; t < TLEN; t += 4) {
        float x0, x1, x2, x3;
        if constexpr (sizeof(HT) == 4) {
            float4 hv = *(const float4*)((const float*)Hp + (size_t)t * HID + (lane << 2));
            x0 = hv.x; x1 = hv.y; x2 = hv.z; x3 = hv.w;
        } else {
            ushort4 hv = *(const ushort4*)((const unsigned short*)Hp + (size_t)t * HID + (lane << 2));
            x0 = bf2f(hv.x); x1 = bf2f(hv.y); x2 = bf2f(hv.z); x3 = bf2f(hv.w);
        }
        float4 hpv = *(const float4*)(&hp[lane << 2]);
        float4 wv = *(const float4*)(&wsc[lane << 2]);
        float s = fast_tanh(x0 + hpv.x) * wv.x
                + fast_tanh(x1 + hpv.y) * wv.y
                + fast_tanh(x2 + hpv.z) * wv.z
                + fast_tanh(x3 + hpv.w) * wv.w;
#pragma unroll
        for (int off = 32; off >= 1; off >>= 1) s += __shfl_xor(s, off);
        if (lane == 0) es[t] = s;
    }
    __syncthreads();
    float e = (tid < TLEN) ? es[tid] : -INFINITY;
    float m = e;
#pragma unroll
    for (int off = 32; off >= 1; off >>= 1) m = fmaxf(m, __shfl_xor(m, off));
    if (lane == 0) red[wave] = m;
    __syncthreads();
    m = fmaxf(fmaxf(red[0], red[1]), fmaxf(red[2], red[3]));
    float p = (tid < TLEN) ? __expf(e - m) : 0.f;
    float ss = p;
#pragma unroll
    for (int off = 32; off >= 1; off >>= 1) ss += __shfl_xor(ss, off);
    if (lane == 0) red[8 + wave] = ss;
    __syncthreads();
    float denom = red[8] + red[9] + red[10] + red[11];
    if (tid < TLEN) es[tid] = p / denom;
    __syncthreads();
    const float* Hb = batchH + (size_t)b * TLEN * DIN;
    float acc0 = 0.f, acc1 = 0.f;
#pragma unroll 4
    for (int t = 0; t < TLEN; ++t) {
        float a = es[t];
        acc0 = fmaf(a, Hb[(size_t)t * DIN + tid], acc0);
        acc1 = fmaf(a, Hb[(size_t)t * DIN + HID + tid], acc1);
    }
    context[(size_t)b * DIN + tid] = acc0;
    context[(size_t)b * DIN + HID + tid] = acc1;
}

// GRU gate math + fused generator: writes hidden and out[b,s,:].
__global__ __launch_bounds__(256)
void gru_gate_gen(const float* __restrict__ gi,   // [B,768] (+b_ih)
                  const float* __restrict__ hg,   // [B,1024]; cols 256.. = gh (+b_hh)
                  float* __restrict__ hidden,     // [B,HID] in/out
                  float* __restrict__ out,        // [B,STEPS,NCLS]
                  const int* __restrict__ text,   // [B,STEPS]
                  int s,
                  const float* __restrict__ W_ih,
                  const float* __restrict__ W_gen,
                  const float* __restrict__ b_gen) {
    const int b = blockIdx.x;
    const int h = threadIdx.x;  // 256
    __shared__ float sh[HID];
    const int ch = text[b * STEPS + s];
    const float* gib = gi + (size_t)b * G3;
    const float* ghb = hg + (size_t)b * 1024 + 256;
    float ir = gib[h]        + W_ih[(size_t)h * GRUIN + DIN + ch];
    float iz = gib[256 + h]  + W_ih[(size_t)(256 + h) * GRUIN + DIN + ch];
    float in_ = gib[512 + h] + W_ih[(size_t)(512 + h) * GRUIN + DIN + ch];
    float hr = ghb[h];
    float hz = ghb[256 + h];
    float hn = ghb[512 + h];
    float r = fast_sigmoid(ir + hr);
    float z = fast_sigmoid(iz + hz);
    float n = fast_tanh(in_ + r * hn);
    float hprev = hidden[b * HID + h];
    float nh = (1.f - z) * n + z * hprev;
    hidden[b * HID + h] = nh;
    sh[h] = nh;
    __syncthreads();
    if (h < NCLS) {
        const float* wg = W_gen + (size_t)h * HID;
        float acc = b_gen[h];
#pragma unroll 4
        for (int k = 0; k < HID; k += 4) {
            float4 w4 = *(const float4*)(wg + k);
            acc = fmaf(sh[k], w4.x, acc);
            acc = fmaf(sh[k + 1], w4.y, acc);
            acc = fmaf(sh[k + 2], w4.z, acc);
            acc = fmaf(sh[k + 3], w4.w, acc);
        }
        out[((size_t)b * STEPS + s) * NCLS + h] = acc;
    }
}

extern "C" void kernel_launch(void* const* d_in, const int* in_sizes, int n_in,
                              void* d_out, int out_size, void* d_ws, size_t ws_size,
                              hipStream_t stream) {
    const float* batch_H = (const float*)d_in[0];
    const int* text      = (const int*)d_in[1];
    const float* W_i2h   = (const float*)d_in[3];
    const float* W_h2h   = (const float*)d_in[4];
    const float* b_h2h   = (const float*)d_in[5];
    const float* W_score = (const float*)d_in[6];
    const float* W_ih    = (const float*)d_in[7];
    const float* W_hh    = (const float*)d_in[8];
    const float* b_ih    = (const float*)d_in[9];
    const float* b_hh    = (const float*)d_in[10];
    const float* W_gen   = (const float*)d_in[11];
    const float* b_gen   = (const float*)d_in[12];
    float* out = (float*)d_out;
    char* ws = (char*)d_ws;

    const size_t nHp = (size_t)BATCH * TLEN * HID;       // 16,777,216 elems
    const size_t small_floats = (size_t)BATCH * HID + BATCH * 1024 + BATCH * DIN
                              + BATCH * G3 + 1024 * HID + 1024;  // 1,573,888
    const size_t need_fp32 = nHp * 4 + small_floats * 4; // 73,404,416 B
    const bool use_fp32 = (ws_size >= need_fp32);

    const size_t hp_bytes = use_fp32 ? nHp * 4 : nHp * 2;
    void* Hproj = (void*)ws;
    float* hidden  = (float*)(ws + hp_bytes);
    float* hg      = hidden + BATCH * HID;
    float* context = hg + BATCH * 1024;
    float* gi      = context + BATCH * DIN;
    float* Wcat    = gi + BATCH * G3;
    float* bcat    = Wcat + 1024 * HID;

    hipLaunchKernelGGL(prep_wcat, dim3(1024), dim3(256), 0, stream,
                       W_h2h, W_hh, b_h2h, b_hh, Wcat, bcat, hidden);

    // H_proj = batch_H @ W_i2h^T   [65536,512] x [256,512]^T
    if (use_fp32) {
        hipLaunchKernelGGL(gemm_nt<float>, dim3((BATCH * TLEN) / BM, HID / BN), dim3(256), 0, stream,
                           batch_H, DIN, W_i2h, DIN, (float*)Hproj, HID, (const float*)nullptr,
                           BATCH * TLEN, HID, DIN);
    } else {
        hipLaunchKernelGGL(gemm_nt<unsigned short>, dim3((BATCH * TLEN) / BM, HID / BN), dim3(256), 0, stream,
                           batch_H, DIN, W_i2h, DIN, (unsigned short*)Hproj, HID, (const float*)nullptr,
                           BATCH * TLEN, HID, DIN);
    }

    for (int s = 0; s < STEPS; ++s) {
        hipLaunchKernelGGL(gemm_nt<float>, dim3(BATCH / BM, 1024 / BN), dim3(256), 0, stream,
                           hidden, HID, Wcat, HID, hg, 1024, bcat, BATCH, 1024, HID);
        if (use_fp32) {
            hipLaunchKernelGGL(attn_step<float>, dim3(BATCH), dim3(256), 0, stream,
                               (const float*)Hproj, batch_H, hg, W_score, context);
        } else {
            hipLaunchKernelGGL(attn_step<unsigned short>, dim3(BATCH), dim3(256), 0, stream,
                               (const unsigned short*)Hproj, batch_H, hg, W_score, context);
        }
        hipLaunchKernelGGL(gemm_nt<float>, dim3(BATCH / BM, G3 / BN), dim3(256), 0, stream,
                           context, DIN, W_ih, GRUIN, gi, G3, b_ih, BATCH, G3, DIN);
        hipLaunchKernelGGL(gru_gate_gen, dim3(BATCH), dim3(HID), 0, stream,
                           gi, hg, hidden, out, text, s, W_ih, W_gen, b_gen);
    }
}

// Round 3
// 2507.745 us; speedup vs baseline: 1.1349x; 1.1349x over previous
//
#include <hip/hip_runtime.h>

#define BATCH 512
#define TLEN 128
#define DIN 512
#define HID 256
#define NCLS 96
#define STEPS 26
#define GRUIN 608
#define G3 768

#define BM 64
#define BN 64
#define BK 16
#define LDS_STRIDE 68

typedef unsigned short ushort_t;
typedef __attribute__((ext_vector_type(8))) short short8v;      // 8 bf16 input frag
typedef __attribute__((ext_vector_type(4))) float f32x4;        // 4 f32 acc frag
typedef __attribute__((ext_vector_type(8))) unsigned short ushort8v;

__device__ __forceinline__ float fast_tanh(float x) {
    return 1.f - 2.f / (__expf(2.f * x) + 1.f);
}
__device__ __forceinline__ float fast_sigmoid(float x) {
    return 1.f / (1.f + __expf(-x));
}
__device__ __forceinline__ ushort_t f2bf_rne(float f) {
    unsigned int u = __float_as_uint(f);
    unsigned int r = (u + 0x7FFFu + ((u >> 16) & 1u)) >> 16;
    return (ushort_t)r;
}
__device__ __forceinline__ float bf2f(ushort_t h) {
    return __uint_as_float(((unsigned int)h) << 16);
}

template <typename OutT>
__device__ __forceinline__ void store_c(OutT* p, float v);
template <> __device__ __forceinline__ void store_c<float>(float* p, float v) { *p = v; }
template <> __device__ __forceinline__ void store_c<ushort_t>(ushort_t* p, float v) { *p = f2bf_rne(v); }

// ---------------- fp32 tiled GEMM (torch-layout B), used for small per-step GEMMs ----------------
template <typename OutT>
__global__ __launch_bounds__(256)
void gemm_nt(const float* __restrict__ A, int lda,
             const float* __restrict__ Bw, int ldb,
             OutT* __restrict__ Cc, int ldc,
             const float* __restrict__ bias,
             int M, int N, int K) {
    __shared__ float As[BK][LDS_STRIDE];
    __shared__ float Bs[BK][LDS_STRIDE];
    const int tid = threadIdx.x;
    const int bm = blockIdx.x * BM;
    const int bn = blockIdx.y * BN;
    const int tx = tid & 15, ty = tid >> 4;
    const int lr = tid >> 2;
    const int lc = (tid & 3) << 2;
    float acc[4][4] = {};
    const int gr = bm + lr;
    const int gn = bn + lr;
    const float* Arow = A + (size_t)gr * lda;
    const float* Brow = Bw + (size_t)gn * ldb;
    for (int k0 = 0; k0 < K; k0 += BK) {
        float4 va = make_float4(0.f, 0.f, 0.f, 0.f);
        float4 vb = make_float4(0.f, 0.f, 0.f, 0.f);
        if (gr < M) va = *(const float4*)(Arow + k0 + lc);
        if (gn < N) vb = *(const float4*)(Brow + k0 + lc);
        As[lc + 0][lr] = va.x; As[lc + 1][lr] = va.y;
        As[lc + 2][lr] = va.z; As[lc + 3][lr] = va.w;
        Bs[lc + 0][lr] = vb.x; Bs[lc + 1][lr] = vb.y;
        Bs[lc + 2][lr] = vb.z; Bs[lc + 3][lr] = vb.w;
        __syncthreads();
#pragma unroll
        for (int k = 0; k < BK; ++k) {
            float4 a4 = *(const float4*)(&As[k][ty << 2]);
            float4 b4 = *(const float4*)(&Bs[k][tx << 2]);
            float a[4] = {a4.x, a4.y, a4.z, a4.w};
            float b[4] = {b4.x, b4.y, b4.z, b4.w};
#pragma unroll
            for (int i = 0; i < 4; ++i)
#pragma unroll
                for (int j = 0; j < 4; ++j)
                    acc[i][j] = fmaf(a[i], b[j], acc[i][j]);
        }
        __syncthreads();
    }
#pragma unroll
    for (int i = 0; i < 4; ++i) {
        int m = bm + (ty << 2) + i;
        if (m >= M) continue;
#pragma unroll
        for (int j = 0; j < 4; ++j) {
            int n = bn + (tx << 2) + j;
            if (n < N) store_c(&Cc[(size_t)m * ldc + n], acc[i][j] + (bias ? bias[n] : 0.f));
        }
    }
}

// ---------------- bf16 MFMA GEMM: C16[M,256] = A16[M,512] @ B16[256,512]^T ----------------
// 128x128 block tile, 4 waves in 2x2, per-wave 64x64 (4x4 frags of 16x16), BK=32.
#define PAD_ROW 40  // ushorts per LDS row (32 data + 8 pad) = 80 B, 16B-aligned
__global__ __launch_bounds__(256)
void hproj_mfma(const ushort_t* __restrict__ A16,
                const ushort_t* __restrict__ B16,
                ushort_t* __restrict__ C16,
                int M) {
    __shared__ ushort_t As[128 * PAD_ROW];
    __shared__ ushort_t Bs[128 * PAD_ROW];
    const int bid = blockIdx.x;
    const int bm = (bid >> 1) * 128;
    const int bn = (bid & 1) * 128;
    const int tid = threadIdx.x;
    const int wid = tid >> 6;
    const int lane = tid & 63;
    const int wr = wid >> 1;   // 0..1
    const int wc = wid & 1;    // 0..1
    const int sr = tid >> 2;   // staging row 0..63
    const int sq = tid & 3;    // 16B quad within 64B K-tile row

    f32x4 acc[4][4] = {};
    const int l15 = lane & 15;
    const int lhi = lane >> 4;

    for (int k0 = 0; k0 < 512; k0 += 32) {
        ushort8v a0 = *(const ushort8v*)(A16 + (size_t)(bm + sr) * 512 + k0 + sq * 8);
        ushort8v a1 = *(const ushort8v*)(A16 + (size_t)(bm + sr + 64) * 512 + k0 + sq * 8);
        ushort8v b0 = *(const ushort8v*)(B16 + (size_t)(bn + sr) * 512 + k0 + sq * 8);
        ushort8v b1 = *(const ushort8v*)(B16 + (size_t)(bn + sr + 64) * 512 + k0 + sq * 8);
        __syncthreads();
        *(ushort8v*)(&As[sr * PAD_ROW + sq * 8]) = a0;
        *(ushort8v*)(&As[(sr + 64) * PAD_ROW + sq * 8]) = a1;
        *(ushort8v*)(&Bs[sr * PAD_ROW + sq * 8]) = b0;
        *(ushort8v*)(&Bs[(sr + 64) * PAD_ROW + sq * 8]) = b1;
        __syncthreads();
        short8v af[4], bfr[4];
#pragma unroll
        for (int i = 0; i < 4; ++i) {
            int arow = wr * 64 + i * 16 + l15;
            af[i] = *(const short8v*)(&As[arow * PAD_ROW + lhi * 8]);
            int brow = wc * 64 + i * 16 + l15;
            bfr[i] = *(const short8v*)(&Bs[brow * PAD_ROW + lhi * 8]);
        }
#pragma unroll
        for (int i = 0; i < 4; ++i)
#pragma unroll
            for (int j = 0; j < 4; ++j)
                acc[i][j] = __builtin_amdgcn_mfma_f32_16x16x32_bf16(af[i], bfr[j], acc[i][j], 0, 0, 0);
    }
    const int cr0 = bm + wr * 64 + lhi * 4;
    const int cc0 = bn + wc * 64 + l15;
#pragma unroll
    for (int i = 0; i < 4; ++i)
#pragma unroll
        for (int j = 0; j < 4; ++j)
#pragma unroll
            for (int p = 0; p < 4; ++p)
                C16[(size_t)(cr0 + i * 16 + p) * 256 + cc0 + j * 16] = f2bf_rne(acc[i][j][p]);
}

// ---------------- fp32 -> bf16 conversion (vectorized, grid-stride) ----------------
__global__ __launch_bounds__(256)
void conv_f2bf(const float* __restrict__ src, ushort_t* __restrict__ dst, int n4) {
    int i = blockIdx.x * 256 + threadIdx.x;
    const int stride = gridDim.x * 256;
    for (; i < n4; i += stride) {
        float4 v = ((const float4*)src)[i];
        ushort4 o;
        o.x = f2bf_rne(v.x); o.y = f2bf_rne(v.y);
        o.z = f2bf_rne(v.z); o.w = f2bf_rne(v.w);
        ((ushort4*)dst)[i] = o;
    }
}

// ---------------- prep: Wcat/bcat pack + hidden zero ----------------
__global__ __launch_bounds__(256)
void prep_wcat(const float* __restrict__ W_h2h, const float* __restrict__ W_hh,
               const float* __restrict__ b_h2h, const float* __restrict__ b_hh,
               float* __restrict__ Wcat, float* __restrict__ bcat,
               float* __restrict__ hidden) {
    int idx = blockIdx.x * 256 + threadIdx.x;
    int r = idx >> 8, c = idx & 255;
    Wcat[idx] = (r < 256) ? W_h2h[r * 256 + c] : W_hh[(r - 256) * 256 + c];
    if (idx < 1024) bcat[idx] = (idx < 256) ? b_h2h[idx] : b_hh[idx - 256];
    if (idx < BATCH * HID) hidden[idx] = 0.f;
}

// ---------------- attention step, all-bf16 streams (plan A) ----------------
__global__ __launch_bounds__(256)
void attn_bf16(const ushort_t* __restrict__ Hp16,  // [B,T,HID] bf16
               const ushort_t* __restrict__ bH16,  // [B,T,DIN] bf16
               const float* __restrict__ hg,       // [B,1024]; cols 0..255 = h_proj
               const float* __restrict__ Wscore,   // [HID]
               float* __restrict__ context) {      // [B,DIN]
    const int b = blockIdx.x;
    const int tid = threadIdx.x;   // 256
    __shared__ float hp[HID];
    __shared__ float wsc[HID];
    __shared__ float es[TLEN];
    __shared__ float red[16];
    hp[tid] = hg[b * 1024 + tid];
    wsc[tid] = Wscore[tid];
    __syncthreads();
    const int wave = tid >> 6;
    const int lane = tid & 63;
    const ushort_t* Hp = Hp16 + (size_t)b * TLEN * HID;
    for (int t = wave; t < TLEN; t += 4) {
        ushort4 hv = *(const ushort4*)(Hp + (size_t)t * HID + (lane << 2));
        float4 hpv = *(const float4*)(&hp[lane << 2]);
        float4 wv = *(const float4*)(&wsc[lane << 2]);
        float s = fast_tanh(bf2f(hv.x) + hpv.x) * wv.x
                + fast_tanh(bf2f(hv.y) + hpv.y) * wv.y
                + fast_tanh(bf2f(hv.z) + hpv.z) * wv.z
                + fast_tanh(bf2f(hv.w) + hpv.w) * wv.w;
#pragma unroll
        for (int off = 32; off >= 1; off >>= 1) s += __shfl_xor(s, off);
        if (lane == 0) es[t] = s;
    }
    __syncthreads();
    float e = (tid < TLEN) ? es[tid] : -INFINITY;
    float m = e;
#pragma unroll
    for (int off = 32; off >= 1; off >>= 1) m = fmaxf(m, __shfl_xor(m, off));
    if (lane == 0) red[wave] = m;
    __syncthreads();
    m = fmaxf(fmaxf(red[0], red[1]), fmaxf(red[2], red[3]));
    float p = (tid < TLEN) ? __expf(e - m) : 0.f;
    float ss = p;
#pragma unroll
    for (int off = 32; off >= 1; off >>= 1) ss += __shfl_xor(ss, off);
    if (lane == 0) red[8 + wave] = ss;
    __syncthreads();
    float denom = red[8] + red[9] + red[10] + red[11];
    if (tid < TLEN) es[tid] = p / denom;
    __syncthreads();
    // context: thread handles cols 2*tid, 2*tid+1 (one u32 load per t)
    const unsigned int* Hb = (const unsigned int*)(bH16 + (size_t)b * TLEN * DIN);
    float acc0 = 0.f, acc1 = 0.f;
#pragma unroll 4
    for (int t = 0; t < TLEN; ++t) {
        float a = es[t];
        unsigned int v = Hb[(size_t)t * (DIN / 2) + tid];
        acc0 = fmaf(a, bf2f((ushort_t)(v & 0xffffu)), acc0);
        acc1 = fmaf(a, bf2f((ushort_t)(v >> 16)), acc1);
    }
    context[(size_t)b * DIN + 2 * tid] = acc0;
    context[(size_t)b * DIN + 2 * tid + 1] = acc1;
}

// ---------------- attention step, plan-B (Hproj fp32-or-bf16, batch_H fp32) ----------------
template <typename HT>
__global__ __launch_bounds__(256)
void attn_step(const HT* __restrict__ Hproj,
               const float* __restrict__ batchH,
               const float* __restrict__ hg,
               const float* __restrict__ Wscore,
               float* __restrict__ context) {
    const int b = blockIdx.x;
    const int tid = threadIdx.x;
    __shared__ float hp[HID];
    __shared__ float wsc[HID];
    __shared__ float es[TLEN];
    __shared__ float red[16];
    hp[tid] = hg[b * 1024 + tid];
    wsc[tid] = Wscore[tid];
    __syncthreads();
    const int wave = tid >> 6;
    const int lane = tid & 63;
    const HT* Hp = Hproj + (size_t)b * TLEN * HID;
    for (int t = wave; t < TLEN; t += 4) {
        float x0, x1, x2, x3;
        if constexpr (sizeof(HT) == 4) {
            float4 hv = *(const float4*)((const float*)Hp + (size_t)t * HID + (lane << 2));
            x0 = hv.x; x1 = hv.y; x2 = hv.z; x3 = hv.w;
        } else {
            ushort4 hv = *(const ushort4*)((const ushort_t*)Hp + (size_t)t * HID + (lane << 2));
            x0 = bf2f(hv.x); x1 = bf2f(hv.y); x2 = bf2f(hv.z); x3 = bf2f(hv.w);
        }
        float4 hpv = *(const float4*)(&hp[lane << 2]);
        float4 wv = *(const float4*)(&wsc[lane << 2]);
        float s = fast_tanh(x0 + hpv.x) * wv.x
                + fast_tanh(x1 + hpv.y) * wv.y
                + fast_tanh(x2 + hpv.z) * wv.z
                + fast_tanh(x3 + hpv.w) * wv.w;
#pragma unroll
        for (int off = 32; off >= 1; off >>= 1) s += __shfl_xor(s, off);
        if (lane == 0) es[t] = s;
    }
    __syncthreads();
    float e = (tid < TLEN) ? es[tid] : -INFINITY;
    float m = e;
#pragma unroll
    for (int off = 32; off >= 1; off >>= 1) m = fmaxf(m, __shfl_xor(m, off));
    if (lane == 0) red[wave] = m;
    __syncthreads();
    m = fmaxf(fmaxf(red[0], red[1]), fmaxf(red[2], red[3]));
    float p = (tid < TLEN) ? __expf(e - m) : 0.f;
    float ss = p;
#pragma unroll
    for (int off = 32; off >= 1; off >>= 1) ss += __shfl_xor(ss, off);
    if (lane == 0) red[8 + wave] = ss;
    __syncthreads();
    float denom = red[8] + red[9] + red[10] + red[11];
    if (tid < TLEN) es[tid] = p / denom;
    __syncthreads();
    const float* Hb = batchH + (size_t)b * TLEN * DIN;
    float acc0 = 0.f, acc1 = 0.f;
#pragma unroll 4
    for (int t = 0; t < TLEN; ++t) {
        float a = es[t];
        acc0 = fmaf(a, Hb[(size_t)t * DIN + tid], acc0);
        acc1 = fmaf(a, Hb[(size_t)t * DIN + HID + tid], acc1);
    }
    context[(size_t)b * DIN + tid] = acc0;
    context[(size_t)b * DIN + HID + tid] = acc1;
}

// ---------------- GRU gates + fused generator ----------------
__global__ __launch_bounds__(256)
void gru_gate_gen(const float* __restrict__ gi,
                  const float* __restrict__ hg,
                  float* __restrict__ hidden,
                  float* __restrict__ out,
                  const int* __restrict__ text,
                  int s,
                  const float* __restrict__ W_ih,
                  const float* __restrict__ W_gen,
                  const float* __restrict__ b_gen) {
    const int b = blockIdx.x;
    const int h = threadIdx.x;
    __shared__ float sh[HID];
    const int ch = text[b * STEPS + s];
    const float* gib = gi + (size_t)b * G3;
    const float* ghb = hg + (size_t)b * 1024 + 256;
    float ir = gib[h]        + W_ih[(size_t)h * GRUIN + DIN + ch];
    float iz = gib[256 + h]  + W_ih[(size_t)(256 + h) * GRUIN + DIN + ch];
    float in_ = gib[512 + h] + W_ih[(size_t)(512 + h) * GRUIN + DIN + ch];
    float hr = ghb[h];
    float hz = ghb[256 + h];
    float hn = ghb[512 + h];
    float r = fast_sigmoid(ir + hr);
    float z = fast_sigmoid(iz + hz);
    float n = fast_tanh(in_ + r * hn);
    float hprev = hidden[b * HID + h];
    float nh = (1.f - z) * n + z * hprev;
    hidden[b * HID + h] = nh;
    sh[h] = nh;
    __syncthreads();
    if (h < NCLS) {
        const float* wg = W_gen + (size_t)h * HID;
        float acc = b_gen[h];
#pragma unroll 4
        for (int k = 0; k < HID; k += 4) {
            float4 w4 = *(const float4*)(wg + k);
            acc = fmaf(sh[k], w4.x, acc);
            acc = fmaf(sh[k + 1], w4.y, acc);
            acc = fmaf(sh[k + 2], w4.z, acc);
            acc = fmaf(sh[k + 3], w4.w, acc);
        }
        out[((size_t)b * STEPS + s) * NCLS + h] = acc;
    }
}

extern "C" void kernel_launch(void* const* d_in, const int* in_sizes, int n_in,
                              void* d_out, int out_size, void* d_ws, size_t ws_size,
                              hipStream_t stream) {
    const float* batch_H = (const float*)d_in[0];
    const int* text      = (const int*)d_in[1];
    const float* W_i2h   = (const float*)d_in[3];
    const float* W_h2h   = (const float*)d_in[4];
    const float* b_h2h   = (const float*)d_in[5];
    const float* W_score = (const float*)d_in[6];
    const float* W_ih    = (const float*)d_in[7];
    const float* W_hh    = (const float*)d_in[8];
    const float* b_ih    = (const float*)d_in[9];
    const float* b_hh    = (const float*)d_in[10];
    const float* W_gen   = (const float*)d_in[11];
    const float* b_gen   = (const float*)d_in[12];
    float* out = (float*)d_out;
    char* ws = (char*)d_ws;

    const size_t nBH = (size_t)BATCH * TLEN * DIN;   // 33,554,432
    const size_t nHp = (size_t)BATCH * TLEN * HID;   // 16,777,216
    const size_t small_floats = (size_t)BATCH * HID + BATCH * 1024 + BATCH * DIN
                              + BATCH * G3 + 1024 * HID + 1024;   // 1,573,888
    const size_t need_A = nBH * 2 + nHp * 2 + (size_t)HID * DIN * 2 + small_floats * 4; // 107,220,992
    const size_t need_B32 = nHp * 4 + small_floats * 4;                                 // 73,404,416

    if (ws_size >= need_A) {
        // ---------------- Plan A: bf16 streams + MFMA Hproj ----------------
        ushort_t* bH16 = (ushort_t*)ws;
        ushort_t* Hp16 = bH16 + nBH;
        ushort_t* Wi16 = Hp16 + nHp;
        float* hidden  = (float*)(Wi16 + (size_t)HID * DIN);
        float* hg      = hidden + BATCH * HID;
        float* context = hg + BATCH * 1024;
        float* gi      = context + BATCH * DIN;
        float* Wcat    = gi + BATCH * G3;
        float* bcat    = Wcat + 1024 * HID;

        hipLaunchKernelGGL(prep_wcat, dim3(1024), dim3(256), 0, stream,
                           W_h2h, W_hh, b_h2h, b_hh, Wcat, bcat, hidden);
        hipLaunchKernelGGL(conv_f2bf, dim3(2048), dim3(256), 0, stream,
                           batch_H, bH16, (int)(nBH / 4));
        hipLaunchKernelGGL(conv_f2bf, dim3(128), dim3(256), 0, stream,
                           W_i2h, Wi16, (int)((size_t)HID * DIN / 4));
        hipLaunchKernelGGL(hproj_mfma, dim3((BATCH * TLEN / 128) * 2), dim3(256), 0, stream,
                           bH16, Wi16, Hp16, BATCH * TLEN);

        for (int s = 0; s < STEPS; ++s) {
            hipLaunchKernelGGL(gemm_nt<float>, dim3(BATCH / BM, 1024 / BN), dim3(256), 0, stream,
                               hidden, HID, Wcat, HID, hg, 1024, bcat, BATCH, 1024, HID);
            hipLaunchKernelGGL(attn_bf16, dim3(BATCH), dim3(256), 0, stream,
                               Hp16, bH16, hg, W_score, context);
            hipLaunchKernelGGL(gemm_nt<float>, dim3(BATCH / BM, G3 / BN), dim3(256), 0, stream,
                               context, DIN, W_ih, GRUIN, gi, G3, b_ih, BATCH, G3, DIN);
            hipLaunchKernelGGL(gru_gate_gen, dim3(BATCH), dim3(HID), 0, stream,
                               gi, hg, hidden, out, text, s, W_ih, W_gen, b_gen);
        }
    } else {
        // ---------------- Plan B: round-2 fallback ----------------
        const bool use_fp32 = (ws_size >= need_B32);
        const size_t hp_bytes = use_fp32 ? nHp * 4 : nHp * 2;
        void* Hproj = (void*)ws;
        float* hidden  = (float*)(ws + hp_bytes);
        float* hg      = hidden + BATCH * HID;
        float* context = hg + BATCH * 1024;
        float* gi      = context + BATCH * DIN;
        float* Wcat    = gi + BATCH * G3;
        float* bcat    = Wcat + 1024 * HID;

        hipLaunchKernelGGL(prep_wcat, dim3(1024), dim3(256), 0, stream,
                           W_h2h, W_hh, b_h2h, b_hh, Wcat, bcat, hidden);
        if (use_fp32) {
            hipLaunchKernelGGL(gemm_nt<float>, dim3((BATCH * TLEN) / BM, HID / BN), dim3(256), 0, stream,
                               batch_H, DIN, W_i2h, DIN, (float*)Hproj, HID, (const float*)nullptr,
                               BATCH * TLEN, HID, DIN);
        } else {
            hipLaunchKernelGGL(gemm_nt<ushort_t>, dim3((BATCH * TLEN) / BM, HID / BN), dim3(256), 0, stream,
                               batch_H, DIN, W_i2h, DIN, (ushort_t*)Hproj, HID, (const float*)nullptr,
                               BATCH * TLEN, HID, DIN);
        }
        for (int s = 0; s < STEPS; ++s) {
            hipLaunchKernelGGL(gemm_nt<float>, dim3(BATCH / BM, 1024 / BN), dim3(256), 0, stream,
                               hidden, HID, Wcat, HID, hg, 1024, bcat, BATCH, 1024, HID);
            if (use_fp32) {
                hipLaunchKernelGGL(attn_step<float>, dim3(BATCH), dim3(256), 0, stream,
                                   (const float*)Hproj, batch_H, hg, W_score, context);
            } else {
                hipLaunchKernelGGL(attn_step<ushort_t>, dim3(BATCH), dim3(256), 0, stream,
                                   (const ushort_t*)Hproj, batch_H, hg, W_score, context);
            }
            hipLaunchKernelGGL(gemm_nt<float>, dim3(BATCH / BM, G3 / BN), dim3(256), 0, stream,
                               context, DIN, W_ih, GRUIN, gi, G3, b_ih, BATCH, G3, DIN);
            hipLaunchKernelGGL(gru_gate_gen, dim3(BATCH), dim3(HID), 0, stream,
                               gi, hg, hidden, out, text, s, W_ih, W_gen, b_gen);
        }
    }
}

// Round 4
// 2132.084 us; speedup vs baseline: 1.3349x; 1.1762x over previous
//
#include <hip/hip_runtime.h>

#define BATCH 512
#define TLEN 128
#define DIN 512
#define HID 256
#define NCLS 96
#define STEPS 26
#define GRUIN 608
#define G3 768

#define BM 64
#define BN 64
#define BK 16
#define LDS_STRIDE 68

typedef unsigned short ushort_t;
typedef __attribute__((ext_vector_type(8))) short short8v;
typedef __attribute__((ext_vector_type(4))) float f32x4;
typedef __attribute__((ext_vector_type(8))) unsigned short ushort8v;

__device__ __forceinline__ float fast_tanh(float x) {
    return 1.f - 2.f / (__expf(2.f * x) + 1.f);
}
__device__ __forceinline__ float fast_sigmoid(float x) {
    return 1.f / (1.f + __expf(-x));
}
__device__ __forceinline__ ushort_t f2bf_rne(float f) {
    unsigned int u = __float_as_uint(f);
    unsigned int r = (u + 0x7FFFu + ((u >> 16) & 1u)) >> 16;
    return (ushort_t)r;
}
__device__ __forceinline__ float bf2f(ushort_t h) {
    return __uint_as_float(((unsigned int)h) << 16);
}
__device__ __forceinline__ float bflo(unsigned int v) {
    return __uint_as_float(v << 16);
}
__device__ __forceinline__ float bfhi(unsigned int v) {
    return __uint_as_float(v & 0xffff0000u);
}

// ================= one-time prep: pack/transpose/convert weights =================
// WcatT16 [256][1024]: WcatT[k][n] = (n<256 ? W_h2h[n][k] : W_hh[n-256][k])  (bf16)
// B16cat  [1024][512]: rows 0..767 = W_ih[:, :512]; rows 768..1023 = W_i2h   (bf16)
// WembT   [96][768]  : WembT[ch][j] = W_ih[j][512+ch] + b_ih[j]              (fp32)
// Wgen16  [96][256]  : bf16 copy of W_gen
__global__ __launch_bounds__(256)
void prep_all(const float* __restrict__ W_h2h, const float* __restrict__ W_hh,
              const float* __restrict__ W_ih, const float* __restrict__ W_i2h,
              const float* __restrict__ b_ih, const float* __restrict__ W_gen,
              ushort_t* __restrict__ WcatT, ushort_t* __restrict__ B16cat,
              float* __restrict__ WembT, ushort_t* __restrict__ Wgen16) {
    int idx = blockIdx.x * 256 + threadIdx.x;
    if (idx < 262144) {
        int k = idx >> 10, n = idx & 1023;
        float v = (n < 256) ? W_h2h[n * 256 + k] : W_hh[(size_t)(n - 256) * 256 + k];
        WcatT[idx] = f2bf_rne(v);
    } else if (idx < 262144 + 524288) {
        int j = idx - 262144;
        int r = j >> 9, c = j & 511;
        float v = (r < 768) ? W_ih[(size_t)r * GRUIN + c] : W_i2h[(size_t)(r - 768) * 512 + c];
        B16cat[j] = f2bf_rne(v);
    } else if (idx < 262144 + 524288 + 73728) {
        int j = idx - (262144 + 524288);
        int ch = j / 768, jj = j - ch * 768;
        WembT[j] = W_ih[(size_t)jj * GRUIN + 512 + ch] + b_ih[jj];
    } else if (idx < 262144 + 524288 + 73728 + 24576) {
        int j = idx - (262144 + 524288 + 73728);
        Wgen16[j] = f2bf_rne(W_gen[j]);
    }
}

// ================= fused MFMA GEMM: C16[65536,1024] = bf16(A_fp32) @ B16^T =================
// cols 0..767 = HW (batch_H @ W_ih512^T), cols 768..1023 = Hproj (batch_H @ W_i2h^T)
#define PAD_ROW 40
__global__ __launch_bounds__(256)
void hwhp_mfma(const float* __restrict__ A,       // [65536,512] fp32
               const ushort_t* __restrict__ B16,  // [1024,512] bf16
               ushort_t* __restrict__ C16) {      // [65536,1024] bf16
    __shared__ ushort_t As[128 * PAD_ROW];
    __shared__ ushort_t Bs[128 * PAD_ROW];
    const int wgid = blockIdx.x;
    // XCD-aware swizzle: the 8 N-blocks of one M-tile land on the same XCD (A-tile L2 reuse)
    const int mt = (wgid & 7) + ((wgid >> 6) << 3);
    const int nt = (wgid >> 3) & 7;
    const int bm = mt * 128, bn = nt * 128;
    const int tid = threadIdx.x;
    const int wid = tid >> 6, lane = tid & 63;
    const int wr = wid >> 1, wc = wid & 1;
    const int sr = tid >> 2, sq = tid & 3;
    f32x4 acc[4][4] = {};
    const int l15 = lane & 15, lhi = lane >> 4;
    for (int k0 = 0; k0 < 512; k0 += 32) {
        const float* a0p = A + (size_t)(bm + sr) * 512 + k0 + sq * 8;
        const float* a1p = A + (size_t)(bm + sr + 64) * 512 + k0 + sq * 8;
        float4 fa0 = *(const float4*)a0p;
        float4 fa1 = *(const float4*)(a0p + 4);
        float4 fc0 = *(const float4*)a1p;
        float4 fc1 = *(const float4*)(a1p + 4);
        ushort8v b0 = *(const ushort8v*)(B16 + (size_t)(bn + sr) * 512 + k0 + sq * 8);
        ushort8v b1 = *(const ushort8v*)(B16 + (size_t)(bn + sr + 64) * 512 + k0 + sq * 8);
        ushort8v ua, uc;
        ua[0] = f2bf_rne(fa0.x); ua[1] = f2bf_rne(fa0.y);
        ua[2] = f2bf_rne(fa0.z); ua[3] = f2bf_rne(fa0.w);
        ua[4] = f2bf_rne(fa1.x); ua[5] = f2bf_rne(fa1.y);
        ua[6] = f2bf_rne(fa1.z); ua[7] = f2bf_rne(fa1.w);
        uc[0] = f2bf_rne(fc0.x); uc[1] = f2bf_rne(fc0.y);
        uc[2] = f2bf_rne(fc0.z); uc[3] = f2bf_rne(fc0.w);
        uc[4] = f2bf_rne(fc1.x); uc[5] = f2bf_rne(fc1.y);
        uc[6] = f2bf_rne(fc1.z); uc[7] = f2bf_rne(fc1.w);
        __syncthreads();
        *(ushort8v*)(&As[sr * PAD_ROW + sq * 8]) = ua;
        *(ushort8v*)(&As[(sr + 64) * PAD_ROW + sq * 8]) = uc;
        *(ushort8v*)(&Bs[sr * PAD_ROW + sq * 8]) = b0;
        *(ushort8v*)(&Bs[(sr + 64) * PAD_ROW + sq * 8]) = b1;
        __syncthreads();
        short8v af[4], bfr[4];
#pragma unroll
        for (int i = 0; i < 4; ++i) {
            int arow = wr * 64 + i * 16 + l15;
            af[i] = *(const short8v*)(&As[arow * PAD_ROW + lhi * 8]);
            int brow = wc * 64 + i * 16 + l15;
            bfr[i] = *(const short8v*)(&Bs[brow * PAD_ROW + lhi * 8]);
        }
#pragma unroll
        for (int i = 0; i < 4; ++i)
#pragma unroll
            for (int j = 0; j < 4; ++j)
                acc[i][j] = __builtin_amdgcn_mfma_f32_16x16x32_bf16(af[i], bfr[j], acc[i][j], 0, 0, 0);
    }
    const int cr0 = bm + wr * 64 + lhi * 4;
    const int cc0 = bn + wc * 64 + l15;
#pragma unroll
    for (int i = 0; i < 4; ++i)
#pragma unroll
        for (int j = 0; j < 4; ++j)
#pragma unroll
            for (int p = 0; p < 4; ++p)
                C16[(size_t)(cr0 + i * 16 + p) * 1024 + cc0 + j * 16] = f2bf_rne(acc[i][j][p]);
}

// ================= persistent decoder: entire 26-step loop, 2 batch rows per block =================
__global__ __launch_bounds__(512)
void decoder_loop(const ushort_t* __restrict__ HWHp,   // [B*T][1024] bf16
                  const ushort_t* __restrict__ WcatT,  // [256][1024] bf16
                  const float* __restrict__ WembT,     // [96][768]
                  const ushort_t* __restrict__ Wgen16, // [96][256] bf16
                  const float* __restrict__ b_h2h,
                  const float* __restrict__ b_hh,
                  const float* __restrict__ Wscore,
                  const float* __restrict__ b_gen,
                  const int* __restrict__ text,        // [B][STEPS]
                  float* __restrict__ out) {           // [B][STEPS][NCLS]
    const int b0 = blockIdx.x * 2;
    const int tid = threadIdx.x;   // 512
    const int wave = tid >> 6;
    const int lane = tid & 63;
    __shared__ __align__(16) float hg[2][1024];
    __shared__ __align__(16) float gi[2][G3];
    __shared__ __align__(16) float hidden[2][HID];
    __shared__ __align__(16) float wsc[HID];
    __shared__ __align__(16) float bc[1024];
    __shared__ float bg[NCLS];
    __shared__ float es[2][TLEN];
    __shared__ float al[2][TLEN];
    __shared__ float red[16];

    if (tid < 256) wsc[tid] = Wscore[tid];
    bc[tid] = (tid < 256) ? b_h2h[tid] : b_hh[tid - 256];
    bc[tid + 512] = b_hh[tid + 256];
    if (tid < NCLS) bg[tid] = b_gen[tid];
    hidden[tid >> 8][tid & 255] = 0.f;
    __syncthreads();

    for (int s = 0; s < STEPS; ++s) {
        // -------- phase 1: hg[g][0..1023] = hidden[g] @ WcatT + bc (h_proj | gh) --------
        {
            float a00 = 0.f, a01 = 0.f, a10 = 0.f, a11 = 0.f;
            const unsigned int* wp = (const unsigned int*)WcatT + tid;
#pragma unroll 8
            for (int k = 0; k < 256; ++k) {
                unsigned int w = wp[k * 512];
                float f0 = bflo(w), f1 = bfhi(w);
                float h0 = hidden[0][k];
                float h1 = hidden[1][k];
                a00 = fmaf(h0, f0, a00); a01 = fmaf(h0, f1, a01);
                a10 = fmaf(h1, f0, a10); a11 = fmaf(h1, f1, a11);
            }
            hg[0][2 * tid]     = a00 + bc[2 * tid];
            hg[0][2 * tid + 1] = a01 + bc[2 * tid + 1];
            hg[1][2 * tid]     = a10 + bc[2 * tid];
            hg[1][2 * tid + 1] = a11 + bc[2 * tid + 1];
        }
        __syncthreads();
        // -------- phase 2: scores e[g][t] = W_score . tanh(Hp[b,t] + h_proj[g]) --------
#pragma unroll 4
        for (int i = 0; i < 32; ++i) {
            int idx = (i << 3) + wave;          // 256 tasks over 8 waves
            int g = idx >> 7, t = idx & 127;
            const ushort_t* row = HWHp + ((size_t)(b0 + g) * TLEN + t) * 1024 + G3;
            ushort4 hv = *(const ushort4*)(row + (lane << 2));
            float4 hpv = *(const float4*)(&hg[g][lane << 2]);
            float4 wv = *(const float4*)(&wsc[lane << 2]);
            float sc = fast_tanh(bf2f(hv.x) + hpv.x) * wv.x
                     + fast_tanh(bf2f(hv.y) + hpv.y) * wv.y
                     + fast_tanh(bf2f(hv.z) + hpv.z) * wv.z
                     + fast_tanh(bf2f(hv.w) + hpv.w) * wv.w;
#pragma unroll
            for (int off = 32; off >= 1; off >>= 1) sc += __shfl_xor(sc, off);
            if (lane == 0) es[g][t] = sc;
        }
        __syncthreads();
        // -------- phase 3: softmax per row (256 threads = 4 waves, 2 waves/row) --------
        float pexp = 0.f, ev = 0.f;
        const int sg = tid >> 7, si = tid & 127;
        if (tid < 256) {
            ev = es[sg][si];
            float mx = ev;
#pragma unroll
            for (int off = 32; off >= 1; off >>= 1) mx = fmaxf(mx, __shfl_xor(mx, off));
            if (lane == 0) red[wave] = mx;
        }
        __syncthreads();
        if (tid < 256) {
            float m = fmaxf(red[sg * 2], red[sg * 2 + 1]);
            pexp = __expf(ev - m);
            float sm = pexp;
#pragma unroll
            for (int off = 32; off >= 1; off >>= 1) sm += __shfl_xor(sm, off);
            if (lane == 0) red[8 + wave] = sm;
        }
        __syncthreads();
        if (tid < 256) {
            float denom = red[8 + sg * 2] + red[8 + sg * 2 + 1];
            al[sg][si] = pexp / denom;
        }
        __syncthreads();
        // -------- phase 4: gi[g][0..767] = sum_t al[g][t] * HW[b_g,t,:] --------
        {
            const int gA = (tid >= 384) ? 1 : 0;
            const int cpA = tid - gA * 384;     // u32 col-pair 0..383
            const unsigned int* rowA = (const unsigned int*)(HWHp + (size_t)(b0 + gA) * TLEN * 1024) + cpA;
            const unsigned int* rowB = (const unsigned int*)(HWHp + (size_t)(b0 + 1) * TLEN * 1024) + (tid + 128);
            float accA0 = 0.f, accA1 = 0.f, accB0 = 0.f, accB1 = 0.f;
#pragma unroll 4
            for (int t = 0; t < TLEN; ++t) {
                unsigned int v = rowA[t * 512];
                float aA = al[gA][t];
                accA0 = fmaf(aA, bflo(v), accA0);
                accA1 = fmaf(aA, bfhi(v), accA1);
                if (tid < 256) {
                    unsigned int v2 = rowB[t * 512];
                    float aB = al[1][t];
                    accB0 = fmaf(aB, bflo(v2), accB0);
                    accB1 = fmaf(aB, bfhi(v2), accB1);
                }
            }
            gi[gA][2 * cpA]     = accA0;
            gi[gA][2 * cpA + 1] = accA1;
            if (tid < 256) {
                gi[1][2 * (tid + 128)]     = accB0;
                gi[1][2 * (tid + 128) + 1] = accB1;
            }
        }
        __syncthreads();
        // -------- phase 5: GRU gates, update hidden --------
        {
            const int g = tid >> 8, h = tid & 255;
            const int ch = text[(b0 + g) * STEPS + s];
            const float* em = WembT + (size_t)ch * G3;
            float ir = gi[g][h]       + em[h]       + hg[g][256 + h];
            float iz = gi[g][256 + h] + em[256 + h] + hg[g][512 + h];
            float in_ = gi[g][512 + h] + em[512 + h];
            float hn = hg[g][768 + h];
            float r = fast_sigmoid(ir);
            float z = fast_sigmoid(iz);
            float n = fast_tanh(in_ + r * hn);
            float nh = (1.f - z) * n + z * hidden[g][h];
            hidden[g][h] = nh;
        }
        __syncthreads();
        // -------- phase 6: generator out[b,s,:] = hidden @ W_gen^T + b_gen --------
        if (tid < 192) {
            const int g = (tid >= 96) ? 1 : 0;
            const int c = tid - g * 96;
            const ushort_t* wrow = Wgen16 + (size_t)c * HID;
            float acc = bg[c];
#pragma unroll 4
            for (int k = 0; k < HID; k += 8) {
                ushort8v w8 = *(const ushort8v*)(wrow + k);
                float4 h0 = *(const float4*)(&hidden[g][k]);
                float4 h1 = *(const float4*)(&hidden[g][k + 4]);
                acc = fmaf(h0.x, bf2f(w8[0]), acc);
                acc = fmaf(h0.y, bf2f(w8[1]), acc);
                acc = fmaf(h0.z, bf2f(w8[2]), acc);
                acc = fmaf(h0.w, bf2f(w8[3]), acc);
                acc = fmaf(h1.x, bf2f(w8[4]), acc);
                acc = fmaf(h1.y, bf2f(w8[5]), acc);
                acc = fmaf(h1.z, bf2f(w8[6]), acc);
                acc = fmaf(h1.w, bf2f(w8[7]), acc);
            }
            out[((size_t)(b0 + g) * STEPS + s) * NCLS + c] = acc;
        }
        __syncthreads();
    }
}

// ================= fallback (round-3 Plan B, validated) =================
template <typename OutT>
__device__ __forceinline__ void store_c(OutT* p, float v);
template <> __device__ __forceinline__ void store_c<float>(float* p, float v) { *p = v; }
template <> __device__ __forceinline__ void store_c<ushort_t>(ushort_t* p, float v) { *p = f2bf_rne(v); }

template <typename OutT>
__global__ __launch_bounds__(256)
void gemm_nt(const float* __restrict__ A, int lda,
             const float* __restrict__ Bw, int ldb,
             OutT* __restrict__ Cc, int ldc,
             const float* __restrict__ bias,
             int M, int N, int K) {
    __shared__ float As[BK][LDS_STRIDE];
    __shared__ float Bs[BK][LDS_STRIDE];
    const int tid = threadIdx.x;
    const int bm = blockIdx.x * BM;
    const int bn = blockIdx.y * BN;
    const int tx = tid & 15, ty = tid >> 4;
    const int lr = tid >> 2;
    const int lc = (tid & 3) << 2;
    float acc[4][4] = {};
    const int gr = bm + lr;
    const int gn = bn + lr;
    const float* Arow = A + (size_t)gr * lda;
    const float* Brow = Bw + (size_t)gn * ldb;
    for (int k0 = 0; k0 < K; k0 += BK) {
        float4 va = make_float4(0.f, 0.f, 0.f, 0.f);
        float4 vb = make_float4(0.f, 0.f, 0.f, 0.f);
        if (gr < M) va = *(const float4*)(Arow + k0 + lc);
        if (gn < N) vb = *(const float4*)(Brow + k0 + lc);
        As[lc + 0][lr] = va.x; As[lc + 1][lr] = va.y;
        As[lc + 2][lr] = va.z; As[lc + 3][lr] = va.w;
        Bs[lc + 0][lr] = vb.x; Bs[lc + 1][lr] = vb.y;
        Bs[lc + 2][lr] = vb.z; Bs[lc + 3][lr] = vb.w;
        __syncthreads();
#pragma unroll
        for (int k = 0; k < BK; ++k) {
            float4 a4 = *(const float4*)(&As[k][ty << 2]);
            float4 b4 = *(const float4*)(&Bs[k][tx << 2]);
            float a[4] = {a4.x, a4.y, a4.z, a4.w};
            float b[4] = {b4.x, b4.y, b4.z, b4.w};
#pragma unroll
            for (int i = 0; i < 4; ++i)
#pragma unroll
                for (int j = 0; j < 4; ++j)
                    acc[i][j] = fmaf(a[i], b[j], acc[i][j]);
        }
        __syncthreads();
    }
#pragma unroll
    for (int i = 0; i < 4; ++i) {
        int m = bm + (ty << 2) + i;
        if (m >= M) continue;
#pragma unroll
        for (int j = 0; j < 4; ++j) {
            int n = bn + (tx << 2) + j;
            if (n < N) store_c(&Cc[(size_t)m * ldc + n], acc[i][j] + (bias ? bias[n] : 0.f));
        }
    }
}

__global__ __launch_bounds__(256)
void prep_wcat(const float* __restrict__ W_h2h, const float* __restrict__ W_hh,
               const float* __restrict__ b_h2h, const float* __restrict__ b_hh,
               float* __restrict__ Wcat, float* __restrict__ bcat,
               float* __restrict__ hidden) {
    int idx = blockIdx.x * 256 + threadIdx.x;
    int r = idx >> 8, c = idx & 255;
    Wcat[idx] = (r < 256) ? W_h2h[r * 256 + c] : W_hh[(r - 256) * 256 + c];
    if (idx < 1024) bcat[idx] = (idx < 256) ? b_h2h[idx] : b_hh[idx - 256];
    if (idx < BATCH * HID) hidden[idx] = 0.f;
}

template <typename HT>
__global__ __launch_bounds__(256)
void attn_step(const HT* __restrict__ Hproj,
               const float* __restrict__ batchH,
               const float* __restrict__ hg,
               const float* __restrict__ Wscore,
               float* __restrict__ context) {
    const int b = blockIdx.x;
    const int tid = threadIdx.x;
    __shared__ float hp[HID];
    __shared__ float wsc[HID];
    __shared__ float es[TLEN];
    __shared__ float red[16];
    hp[tid] = hg[b * 1024 + tid];
    wsc[tid] = Wscore[tid];
    __syncthreads();
    const int wave = tid >> 6;
    const int lane = tid & 63;
    const HT* Hp = Hproj + (size_t)b * TLEN * HID;
    for (int t = wave; t < TLEN; t += 4) {
        float x0, x1, x2, x3;
        if constexpr (sizeof(HT) == 4) {
            float4 hv = *(const float4*)((const float*)Hp + (size_t)t * HID + (lane << 2));
            x0 = hv.x; x1 = hv.y; x2 = hv.z; x3 = hv.w;
        } else {
            ushort4 hv = *(const ushort4*)((const ushort_t*)Hp + (size_t)t * HID + (lane << 2));
            x0 = bf2f(hv.x); x1 = bf2f(hv.y); x2 = bf2f(hv.z); x3 = bf2f(hv.w);
        }
        float4 hpv = *(const float4*)(&hp[lane << 2]);
        float4 wv = *(const float4*)(&wsc[lane << 2]);
        float sc = fast_tanh(x0 + hpv.x) * wv.x
                 + fast_tanh(x1 + hpv.y) * wv.y
                 + fast_tanh(x2 + hpv.z) * wv.z
                 + fast_tanh(x3 + hpv.w) * wv.w;
#pragma unroll
        for (int off = 32; off >= 1; off >>= 1) sc += __shfl_xor(sc, off);
        if (lane == 0) es[t] = sc;
    }
    __syncthreads();
    float e = (tid < TLEN) ? es[tid] : -INFINITY;
    float m = e;
#pragma unroll
    for (int off = 32; off >= 1; off >>= 1) m = fmaxf(m, __shfl_xor(m, off));
    if (lane == 0) red[wave] = m;
    __syncthreads();
    m = fmaxf(fmaxf(red[0], red[1]), fmaxf(red[2], red[3]));
    float p = (tid < TLEN) ? __expf(e - m) : 0.f;
    float ss = p;
#pragma unroll
    for (int off = 32; off >= 1; off >>= 1) ss += __shfl_xor(ss, off);
    if (lane == 0) red[8 + wave] = ss;
    __syncthreads();
    float denom = red[8] + red[9] + red[10] + red[11];
    if (tid < TLEN) es[tid] = p / denom;
    __syncthreads();
    const float* Hb = batchH + (size_t)b * TLEN * DIN;
    float acc0 = 0.f, acc1 = 0.f;
#pragma unroll 4
    for (int t = 0; t < TLEN; ++t) {
        float a = es[t];
        acc0 = fmaf(a, Hb[(size_t)t * DIN + tid], acc0);
        acc1 = fmaf(a, Hb[(size_t)t * DIN + HID + tid], acc1);
    }
    context[(size_t)b * DIN + tid] = acc0;
    context[(size_t)b * DIN + HID + tid] = acc1;
}

__global__ __launch_bounds__(256)
void gru_gate_gen(const float* __restrict__ gi,
                  const float* __restrict__ hg,
                  float* __restrict__ hidden,
                  float* __restrict__ out,
                  const int* __restrict__ text,
                  int s,
                  const float* __restrict__ W_ih,
                  const float* __restrict__ W_gen,
                  const float* __restrict__ b_gen) {
    const int b = blockIdx.x;
    const int h = threadIdx.x;
    __shared__ float sh[HID];
    const int ch = text[b * STEPS + s];
    const float* gib = gi + (size_t)b * G3;
    const float* ghb = hg + (size_t)b * 1024 + 256;
    float ir = gib[h]        + W_ih[(size_t)h * GRUIN + DIN + ch];
    float iz = gib[256 + h]  + W_ih[(size_t)(256 + h) * GRUIN + DIN + ch];
    float in_ = gib[512 + h] + W_ih[(size_t)(512 + h) * GRUIN + DIN + ch];
    float hr = ghb[h];
    float hz = ghb[256 + h];
    float hn = ghb[512 + h];
    float r = fast_sigmoid(ir + hr);
    float z = fast_sigmoid(iz + hz);
    float n = fast_tanh(in_ + r * hn);
    float hprev = hidden[b * HID + h];
    float nh = (1.f - z) * n + z * hprev;
    hidden[b * HID + h] = nh;
    sh[h] = nh;
    __syncthreads();
    if (h < NCLS) {
        const float* wg = W_gen + (size_t)h * HID;
        float acc = b_gen[h];
#pragma unroll 4
        for (int k = 0; k < HID; k += 4) {
            float4 w4 = *(const float4*)(wg + k);
            acc = fmaf(sh[k], w4.x, acc);
            acc = fmaf(sh[k + 1], w4.y, acc);
            acc = fmaf(sh[k + 2], w4.z, acc);
            acc = fmaf(sh[k + 3], w4.w, acc);
        }
        out[((size_t)b * STEPS + s) * NCLS + h] = acc;
    }
}

extern "C" void kernel_launch(void* const* d_in, const int* in_sizes, int n_in,
                              void* d_out, int out_size, void* d_ws, size_t ws_size,
                              hipStream_t stream) {
    const float* batch_H = (const float*)d_in[0];
    const int* text      = (const int*)d_in[1];
    const float* W_i2h   = (const float*)d_in[3];
    const float* W_h2h   = (const float*)d_in[4];
    const float* b_h2h   = (const float*)d_in[5];
    const float* W_score = (const float*)d_in[6];
    const float* W_ih    = (const float*)d_in[7];
    const float* W_hh    = (const float*)d_in[8];
    const float* b_ih    = (const float*)d_in[9];
    const float* b_hh    = (const float*)d_in[10];
    const float* W_gen   = (const float*)d_in[11];
    const float* b_gen   = (const float*)d_in[12];
    float* out = (float*)d_out;
    char* ws = (char*)d_ws;

    const size_t M = (size_t)BATCH * TLEN;              // 65536
    const size_t hwhp_bytes  = M * 1024 * 2;            // 134,217,728
    const size_t b16cat_off  = hwhp_bytes;              // 1,048,576
    const size_t wcatT_off   = b16cat_off + 1048576;    // 524,288
    const size_t wgen16_off  = wcatT_off + 524288;      // 49,152
    const size_t wembT_off   = wgen16_off + 49152;      // 294,912
    const size_t need_new    = wembT_off + 294912;      // 136,134,656

    if (ws_size >= need_new) {
        ushort_t* HWHp   = (ushort_t*)ws;
        ushort_t* B16cat = (ushort_t*)(ws + b16cat_off);
        ushort_t* WcatT  = (ushort_t*)(ws + wcatT_off);
        ushort_t* Wgen16 = (ushort_t*)(ws + wgen16_off);
        float*    WembT  = (float*)(ws + wembT_off);

        hipLaunchKernelGGL(prep_all, dim3(3456), dim3(256), 0, stream,
                           W_h2h, W_hh, W_ih, W_i2h, b_ih, W_gen,
                           WcatT, B16cat, WembT, Wgen16);
        hipLaunchKernelGGL(hwhp_mfma, dim3((M / 128) * 8), dim3(256), 0, stream,
                           batch_H, B16cat, HWHp);
        hipLaunchKernelGGL(decoder_loop, dim3(BATCH / 2), dim3(512), 0, stream,
                           HWHp, WcatT, WembT, Wgen16, b_h2h, b_hh, W_score, b_gen,
                           text, out);
        return;
    }

    // ---------------- fallback: round-3 Plan B ----------------
    const size_t nHp = M * HID;
    const size_t small_floats = (size_t)BATCH * HID + BATCH * 1024 + BATCH * DIN
                              + BATCH * G3 + 1024 * HID + 1024;
    const size_t need_B32 = nHp * 4 + small_floats * 4;
    const bool use_fp32 = (ws_size >= need_B32);
    const size_t hp_bytes = use_fp32 ? nHp * 4 : nHp * 2;
    void* Hproj = (void*)ws;
    float* hidden  = (float*)(ws + hp_bytes);
    float* hg      = hidden + BATCH * HID;
    float* context = hg + BATCH * 1024;
    float* gi      = context + BATCH * DIN;
    float* Wcat    = gi + BATCH * G3;
    float* bcat    = Wcat + 1024 * HID;

    hipLaunchKernelGGL(prep_wcat, dim3(1024), dim3(256), 0, stream,
                       W_h2h, W_hh, b_h2h, b_hh, Wcat, bcat, hidden);
    if (use_fp32) {
        hipLaunchKernelGGL(gemm_nt<float>, dim3(M / BM, HID / BN), dim3(256), 0, stream,
                           batch_H, DIN, W_i2h, DIN, (float*)Hproj, HID, (const float*)nullptr,
                           (int)M, HID, DIN);
    } else {
        hipLaunchKernelGGL(gemm_nt<ushort_t>, dim3(M / BM, HID / BN), dim3(256), 0, stream,
                           batch_H, DIN, W_i2h, DIN, (ushort_t*)Hproj, HID, (const float*)nullptr,
                           (int)M, HID, DIN);
    }
    for (int s = 0; s < STEPS; ++s) {
        hipLaunchKernelGGL(gemm_nt<float>, dim3(BATCH / BM, 1024 / BN), dim3(256), 0, stream,
                           hidden, HID, Wcat, HID, hg, 1024, bcat, BATCH, 1024, HID);
        if (use_fp32) {
            hipLaunchKernelGGL(attn_step<float>, dim3(BATCH), dim3(256), 0, stream,
                               (const float*)Hproj, batch_H, hg, W_score, context);
        } else {
            hipLaunchKernelGGL(attn_step<ushort_t>, dim3(BATCH), dim3(256), 0, stream,
                               (const ushort_t*)Hproj, batch_H, hg, W_score, context);
        }
        hipLaunchKernelGGL(gemm_nt<float>, dim3(BATCH / BM, G3 / BN), dim3(256), 0, stream,
                           context, DIN, W_ih, GRUIN, gi, G3, b_ih, BATCH, G3, DIN);
        hipLaunchKernelGGL(gru_gate_gen, dim3(BATCH), dim3(HID), 0, stream,
                           gi, hg, hidden, out, text, s, W_ih, W_gen, b_gen);
    }
}